// Round 1
// 637.686 us; speedup vs baseline: 1.0749x; 1.0749x over previous
//
#include <hip/hip_runtime.h>

#define NPTS 100          // points kept per cloud
#define P_F4 2500         // 10000 points / 4 per float4

// ---------------- Kernel F: foveate (ONE WAVE per batch, 64-thread block) ---
// 64-thread blocks decouple waves: an early-exit wave retires immediately
// instead of waiting at __syncthreads for a worst-case (40-iteration) sibling
// wave in the same block. Depth-2 prefetch keeps 2 iterations of loads in
// flight (6 float4 in regs) to halve the per-iteration HBM-latency stall.
// Output layout: phi4[g*B + b] = float4{phi[4g..4g+3]} (g in [0,75)) so the
// MLP reads one coalesced 16B vector per lane per group.
__global__ __launch_bounds__(64) void foveate_kernel(
    const float* __restrict__ x,     // (B,3,10000)
    const float* __restrict__ l,     // (B,3)
    float4* __restrict__ phi4,       // (75,B) float4
    int B)
{
    const int lane = threadIdx.x;
    const int b    = blockIdx.x;

    __shared__ __align__(16) float s_phi[3 * NPTS];  // [axis*100 + j]

    const float lx = l[b * 3 + 0];
    const float ly = l[b * 3 + 1];
    const float lz = l[b * 3 + 2];
    const float lox = lx - 0.25f, hix = lx + 0.25f;  // same fp32 arithmetic as ref
    const float loy = ly - 0.25f, hiy = ly + 0.25f;
    const float loz = lz - 0.25f, hiz = lz + 0.25f;

    const float4* xr = (const float4*)(x + (size_t)b * 30000);  // rows: 0 / 2500 / 5000 f4

    // depth-2 prefetch: a0 holds iteration base=0, a1 holds base=64
    float4 a0 = xr[lane], c0 = xr[P_F4 + lane], d0 = xr[2 * P_F4 + lane];
    int nf1 = 64 + lane; int nc1 = (nf1 < P_F4) ? nf1 : (P_F4 - 1);
    float4 a1 = xr[nc1], c1 = xr[P_F4 + nc1], d1 = xr[2 * P_F4 + nc1];

    int cnt = 0;  // wave-uniform running in-box count
    for (int base = 0; base < P_F4; base += 64) {
        const bool v = (base + lane < P_F4);
        const float4 ca = a0, cc = c0, cd = d0;
        a0 = a1; c0 = c1; d0 = d1;
        if (base + 128 < P_F4) {  // uniform: prefetch iteration base+128
            int nf = base + 128 + lane;
            int nfc = (nf < P_F4) ? nf : (P_F4 - 1);
            a1 = xr[nfc]; c1 = xr[P_F4 + nfc]; d1 = xr[2 * P_F4 + nfc];
        }
        const bool in0 = v && ca.x >= lox && ca.x <= hix && cc.x >= loy && cc.x <= hiy && cd.x >= loz && cd.x <= hiz;
        const bool in1 = v && ca.y >= lox && ca.y <= hix && cc.y >= loy && cc.y <= hiy && cd.y >= loz && cd.y <= hiz;
        const bool in2 = v && ca.z >= lox && ca.z <= hix && cc.z >= loy && cc.z <= hiy && cd.z >= loz && cd.z <= hiz;
        const bool in3 = v && ca.w >= lox && ca.w <= hix && cc.w >= loy && cc.w <= hiy && cd.w >= loz && cd.w <= hiz;

        const unsigned long long m0 = __ballot(in0);
        const unsigned long long m1 = __ballot(in1);
        const unsigned long long m2 = __ballot(in2);
        const unsigned long long m3 = __ballot(in3);
        const unsigned long long below = (1ull << lane) - 1ull;

        // point order is lane-major (lane L owns points 4L..4L+3): all of
        // lanes <L precede lane L's points; sub-index order within lane.
        int pos = cnt + __popcll(m0 & below) + __popcll(m1 & below) +
                        __popcll(m2 & below) + __popcll(m3 & below);
        if (in0) { if (pos < NPTS) { s_phi[pos] = ca.x; s_phi[NPTS + pos] = cc.x; s_phi[2 * NPTS + pos] = cd.x; } ++pos; }
        if (in1) { if (pos < NPTS) { s_phi[pos] = ca.y; s_phi[NPTS + pos] = cc.y; s_phi[2 * NPTS + pos] = cd.y; } ++pos; }
        if (in2) { if (pos < NPTS) { s_phi[pos] = ca.z; s_phi[NPTS + pos] = cc.z; s_phi[2 * NPTS + pos] = cd.z; } ++pos; }
        if (in3) { if (pos < NPTS) { s_phi[pos] = ca.w; s_phi[NPTS + pos] = cc.w; s_phi[2 * NPTS + pos] = cd.w; } ++pos; }

        cnt += __popcll(m0) + __popcll(m1) + __popcll(m2) + __popcll(m3);
        if (cnt >= NPTS) break;  // wave-uniform exit
    }

    __syncthreads();  // single-wave block: trivially cheap, orders LDS

    const int n = (cnt < NPTS) ? cnt : NPTS;
    if (n == 0) {
        for (int j = lane; j < 3 * NPTS; j += 64) s_phi[j] = 0.0f;
    } else if (n < NPTS) {
        // wrap: idx[j] = inside_idx[j % n]; reads [0,n) writes [n,NPTS) — disjoint
        for (int j = n + lane; j < NPTS; j += 64) {
            const int src = j % n;
            s_phi[j]            = s_phi[src];
            s_phi[NPTS + j]     = s_phi[NPTS + src];
            s_phi[2 * NPTS + j] = s_phi[2 * NPTS + src];
        }
    }
    __syncthreads();

    // vector store: group g = phi[4g..4g+3]; 16B per lane
    const float4* sp = (const float4*)s_phi;
    for (int g = lane; g < 75; g += 64)
        phi4[(size_t)g * B + b] = sp[g];
}

// ---------------- Kernel A: h1 = relu(phi@W1^T+b1), lo = relu(l@W2^T+b2) ----
// lane = batch column (activation traffic coalesced, 16B/lane); weights are
// wave-uniform s_load_dwordx4 broadcasts. Grid = 8 k-groups x 64 col-groups
// = 512 blocks (2 blocks/CU, 2 waves/SIMD) — was 128 blocks (half-idle chip).
// Each wave owns 4 output rows; 75 float4 loads replace 300 scalar loads.
__global__ __launch_bounds__(256) void mlp1_kernel(
    const float4* __restrict__ phi4, // (75,B)
    const float* __restrict__ l,     // (B,3)
    const float* __restrict__ W1,    // (128,300)
    const float* __restrict__ b1,    // (128)
    const float* __restrict__ W2,    // (128,3)
    const float* __restrict__ b2,    // (128)
    float4* __restrict__ h14,        // (32,B): h14[k>>2][col][k&3]
    float4* __restrict__ lo4,        // (32,B)
    int B)
{
    const int tid  = threadIdx.x;
    const int wv   = tid >> 6;
    const int lane = tid & 63;
    const int BG   = B >> 6;
    const int bg   = blockIdx.x % BG;
    const int kh   = blockIdx.x / BG;        // 0..7
    const int col  = bg * 64 + lane;
    const int k0   = __builtin_amdgcn_readfirstlane(kh * 16 + wv * 4);

    float acc[4];
    #pragma unroll
    for (int kk = 0; kk < 4; ++kk) acc[kk] = b1[k0 + kk];

    const float* __restrict__ w1 = W1 + (size_t)k0 * 300;
    #pragma unroll 5
    for (int g = 0; g < 75; ++g) {
        const float4 p = phi4[(size_t)g * B + col];   // coalesced 1KB per wave
        #pragma unroll
        for (int kk = 0; kk < 4; ++kk) {
            const float* __restrict__ wr = w1 + kk * 300 + 4 * g;  // s_load_dwordx4
            acc[kk] = fmaf(p.x, wr[0], acc[kk]);
            acc[kk] = fmaf(p.y, wr[1], acc[kk]);
            acc[kk] = fmaf(p.z, wr[2], acc[kk]);
            acc[kk] = fmaf(p.w, wr[3], acc[kk]);
        }
    }
    float4 h;
    h.x = fmaxf(acc[0], 0.0f); h.y = fmaxf(acc[1], 0.0f);
    h.z = fmaxf(acc[2], 0.0f); h.w = fmaxf(acc[3], 0.0f);
    h14[(size_t)(k0 >> 2) * B + col] = h;             // one coalesced 16B store

    const float l0 = l[col * 3 + 0];
    const float l1 = l[col * 3 + 1];
    const float l2 = l[col * 3 + 2];
    float lo[4];
    #pragma unroll
    for (int kk = 0; kk < 4; ++kk) {
        const int k = k0 + kk;
        lo[kk] = fmaxf(b2[k] + l0 * W2[k * 3 + 0] + l1 * W2[k * 3 + 1] + l2 * W2[k * 3 + 2], 0.0f);
    }
    lo4[(size_t)(k0 >> 2) * B + col] = make_float4(lo[0], lo[1], lo[2], lo[3]);
}

// ---------------- Kernel B: out = relu(h1@W3^T + lo@W4^T + b3 + b4) --------
// Grid = 8 m-groups x 64 col-groups = 512 blocks (2/CU). Wave owns 8 output
// rows; 32 float4-pair loads replace 256 scalar loads. Per-lane output rows
// are contiguous (32B), so the store needs no LDS transpose at all.
__global__ __launch_bounds__(256) void mlp2_kernel(
    const float4* __restrict__ h14,  // (32,B)
    const float4* __restrict__ lo4,  // (32,B)
    const float* __restrict__ W3,    // (256,128)
    const float* __restrict__ b3,    // (256)
    const float* __restrict__ W4,    // (256,128)
    const float* __restrict__ b4,    // (256)
    float* __restrict__ out,         // (B,256)
    int B)
{
    const int tid  = threadIdx.x;
    const int wv   = tid >> 6;
    const int lane = tid & 63;
    const int BG   = B >> 6;
    const int bg   = blockIdx.x % BG;
    const int mq   = blockIdx.x / BG;        // 0..7
    const int col  = bg * 64 + lane;
    const int m0   = __builtin_amdgcn_readfirstlane(mq * 32 + wv * 8);

    float acc[8];
    #pragma unroll
    for (int mm = 0; mm < 8; ++mm) acc[mm] = b3[m0 + mm] + b4[m0 + mm];

    const float* __restrict__ w3 = W3 + (size_t)m0 * 128;
    const float* __restrict__ w4 = W4 + (size_t)m0 * 128;
    #pragma unroll 4
    for (int kb = 0; kb < 32; ++kb) {
        const float4 h = h14[(size_t)kb * B + col];   // coalesced 1KB
        const float4 v = lo4[(size_t)kb * B + col];   // coalesced 1KB
        #pragma unroll
        for (int mm = 0; mm < 8; ++mm) {
            const float* __restrict__ r3 = w3 + mm * 128 + 4 * kb;  // s_load_dwordx4
            const float* __restrict__ r4 = w4 + mm * 128 + 4 * kb;
            acc[mm] = fmaf(h.x, r3[0], fmaf(v.x, r4[0], acc[mm]));
            acc[mm] = fmaf(h.y, r3[1], fmaf(v.y, r4[1], acc[mm]));
            acc[mm] = fmaf(h.z, r3[2], fmaf(v.z, r4[2], acc[mm]));
            acc[mm] = fmaf(h.w, r3[3], fmaf(v.w, r4[3], acc[mm]));
        }
    }

    // per-lane contiguous 32B of the output row: two float4 stores, no LDS
    float4* orow = (float4*)(out + (size_t)col * 256 + m0);  // m0 % 8 == 0 -> 32B aligned
    orow[0] = make_float4(fmaxf(acc[0], 0.0f), fmaxf(acc[1], 0.0f),
                          fmaxf(acc[2], 0.0f), fmaxf(acc[3], 0.0f));
    orow[1] = make_float4(fmaxf(acc[4], 0.0f), fmaxf(acc[5], 0.0f),
                          fmaxf(acc[6], 0.0f), fmaxf(acc[7], 0.0f));
}

extern "C" void kernel_launch(void* const* d_in, const int* in_sizes, int n_in,
                              void* d_out, int out_size, void* d_ws, size_t ws_size,
                              hipStream_t stream) {
    const float* x  = (const float*)d_in[0];
    const float* l  = (const float*)d_in[1];
    const float* W1 = (const float*)d_in[2];
    const float* b1 = (const float*)d_in[3];
    const float* W2 = (const float*)d_in[4];
    const float* b2 = (const float*)d_in[5];
    const float* W3 = (const float*)d_in[6];
    const float* b3 = (const float*)d_in[7];
    const float* W4 = (const float*)d_in[8];
    const float* b4 = (const float*)d_in[9];
    float* out = (float*)d_out;

    const int B = in_sizes[1] / 3;  // 4096

    float* phiT = (float*)d_ws;            // 75*B float4 = 300*B floats (4.9 MB)
    float* h1T  = phiT + (size_t)300 * B;  // 32*B float4  (2.0 MB)
    float* loT  = h1T  + (size_t)128 * B;  // 32*B float4  (2.0 MB)

    foveate_kernel<<<B, 64, 0, stream>>>(x, l, (float4*)phiT, B);
    mlp1_kernel<<<8 * (B / 64), 256, 0, stream>>>((const float4*)phiT, l, W1, b1, W2, b2,
                                                  (float4*)h1T, (float4*)loT, B);
    mlp2_kernel<<<8 * (B / 64), 256, 0, stream>>>((const float4*)h1T, (const float4*)loT,
                                                  W3, b3, W4, b4, out, B);
}